// Round 4
// baseline (82.105 us; speedup 1.0000x reference)
//
#include <hip/hip_runtime.h>

#define NV 4096
#define NF 2048
#define ISZ 256
#define OSZ 128
#define TILE 16
#define SLICES 16
#define CHUNK 128          // NF / SLICES
#define FAR_P 100.0f
#define NEAR_P 0.1f

// ---------------- projection ----------------
__device__ __forceinline__ float3 project_one(
    const float* __restrict__ verts, int i,
    const float* __restrict__ Km, const float* __restrict__ Rm,
    const float* __restrict__ tv, const float* __restrict__ dc)
{
    float x = verts[3*i+0], y = verts[3*i+1], z = verts[3*i+2];
    float vx = x*Rm[0] + y*Rm[1] + z*Rm[2] + tv[0];
    float vy = x*Rm[3] + y*Rm[4] + z*Rm[5] + tv[1];
    float vz = x*Rm[6] + y*Rm[7] + z*Rm[8] + tv[2];
    float zd = vz + 1e-5f;
    float x_ = vx / zd;
    float y_ = vy / zd;
    float r2 = x_*x_ + y_*y_;
    float k1 = dc[0], k2 = dc[1], p1 = dc[2], p2 = dc[3], k3 = dc[4];
    float radial = 1.0f + k1*r2 + k2*r2*r2 + k3*r2*r2*r2;
    float x__ = x_*radial + 2.0f*p1*x_*y_ + p2*(r2 + 2.0f*x_*x_);
    float y__ = y_*radial + p1*(r2 + 2.0f*y_*y_) + 2.0f*p2*x_*y_;
    float u  = x__*Km[0] + y__*Km[1] + Km[2];
    float vv = x__*Km[3] + y__*Km[4] + Km[5];
    vv = 1024.0f - vv;
    u  = 2.0f*(u  - 512.0f) / 1024.0f;
    vv = 2.0f*(vv - 512.0f) / 1024.0f;
    return make_float3(u, vv, vz);
}

// ---------------- kernel 1: setup + inits (fused) ----------------
// grid = 256 blocks x 256 threads.
//   every block: writes 256 ints of zbuf = FAR
//   block 8:     zeroes the 256 tile counters
//   blocks 0..7: project + set up face (bid*256+tid), then block-bbox -> gb[bid]
__global__ __launch_bounds__(256) void setup_kernel(
    const int* __restrict__ faces, const float* __restrict__ verts,
    const float* __restrict__ Km, const float* __restrict__ Rm,
    const float* __restrict__ tv, const float* __restrict__ dc,
    float4* __restrict__ e0, float4* __restrict__ e1,
    float* __restrict__ rz2, float4* __restrict__ bb,
    int* __restrict__ zbuf, int* __restrict__ tilecnt,
    float4* __restrict__ gb)
{
    const int tid = threadIdx.x, bid = blockIdx.x;
    zbuf[bid*256 + tid] = __float_as_int(FAR_P);
    if (bid == 8) tilecnt[tid] = 0;
    if (bid >= NF/256) return;

    int f = bid*256 + tid;
    float3 p0 = project_one(verts, faces[3*f+0], Km, Rm, tv, dc);
    float3 p1 = project_one(verts, faces[3*f+1], Km, Rm, tv, dc);
    float3 p2 = project_one(verts, faces[3*f+2], Km, Rm, tv, dc);
    float minx = fminf(p0.x, fminf(p1.x, p2.x)) - 1e-4f;
    float maxx = fmaxf(p0.x, fmaxf(p1.x, p2.x)) + 1e-4f;
    float miny = fminf(p0.y, fminf(p1.y, p2.y)) - 1e-4f;
    float maxy = fmaxf(p0.y, fmaxf(p1.y, p2.y)) + 1e-4f;
    e0[f]  = make_float4(p0.x, p0.y, p1.x, p1.y);
    e1[f]  = make_float4(p2.x, p2.y, 1.0f/p0.z, 1.0f/p1.z);
    rz2[f] = 1.0f/p2.z;
    bb[f]  = make_float4(minx, maxx, miny, maxy);

    // block-level scene bbox (no atomics; raster reduces the 8 entries)
    float bmx = minx, bMx = maxx, bmy = miny, bMy = maxy;
    #pragma unroll
    for (int off = 32; off; off >>= 1) {
        bmx = fminf(bmx, __shfl_xor(bmx, off));
        bMx = fmaxf(bMx, __shfl_xor(bMx, off));
        bmy = fminf(bmy, __shfl_xor(bmy, off));
        bMy = fmaxf(bMy, __shfl_xor(bMy, off));
    }
    __shared__ float4 s_w[4];
    if ((tid & 63) == 0) s_w[tid >> 6] = make_float4(bmx, bMx, bmy, bMy);
    __syncthreads();
    if (tid == 0) {
        float4 a = s_w[0];
        #pragma unroll
        for (int w = 1; w < 4; ++w) {
            float4 c = s_w[w];
            a.x = fminf(a.x, c.x); a.y = fmaxf(a.y, c.y);
            a.z = fminf(a.z, c.z); a.w = fmaxf(a.w, c.w);
        }
        gb[bid] = a;
    }
}

// ---------------- kernel 2: raster + fused downsample ----------------
// reference-exact edge/area arithmetic — do not reorder
#define EVAL(K, ZM) { \
    float4 q0 = s_e0[K]; float4 q1 = s_e1[K]; float rz = s_rz2[K]; \
    float dx0 = q0.x - xp, dy0 = q0.y - yp; \
    float dx1 = q0.z - xp, dy1 = q0.w - yp; \
    float dx2 = q1.x - xp, dy2 = q1.y - yp; \
    float w0 = dx1*dy2 - dx2*dy1; \
    float w1 = dx2*dy0 - dx0*dy2; \
    float w2 = dx0*dy1 - dx1*dy0; \
    float area = (w0 + w1) + w2; \
    bool ok = fabsf(area) > 1e-10f; \
    float inv = __builtin_amdgcn_rcpf(ok ? area : 1.0f); \
    float b0 = w0*inv, b1 = w1*inv, b2 = w2*inv; \
    bool inside = ok && (b0 >= 0.0f) && (b1 >= 0.0f) && (b2 >= 0.0f); \
    float zinv = b0*q1.z + b1*q1.w + b2*rz; \
    float zz = (fabsf(zinv) > 1e-10f) ? __builtin_amdgcn_rcpf(zinv) : 1.0f; \
    bool valid = inside && (zz > NEAR_P) && (zz < FAR_P); \
    ZM = fminf(ZM, valid ? zz : FAR_P); }

__global__ __launch_bounds__(256) void raster_kernel(
    const float4* __restrict__ e0, const float4* __restrict__ e1,
    const float* __restrict__ rz2, const float4* __restrict__ bb,
    const float4* __restrict__ gb,
    int* __restrict__ zbuf, int* __restrict__ tilecnt,
    float* __restrict__ out)
{
    __shared__ float4 s_e0[CHUNK];
    __shared__ float4 s_e1[CHUNK];
    __shared__ float  s_rz2[CHUNK];
    __shared__ float2 s_bby[CHUNK];
    __shared__ unsigned short s_list[CHUNK];
    __shared__ int s_cnt;
    __shared__ int s_old;

    const int tid  = threadIdx.x;
    const int bid  = blockIdx.x;
    const int slice = bid & (SLICES - 1);
    const int tileL = bid >> 4;
    const int tileX = tileL & 15, tileY = tileL >> 4;
    const int tx = tid & 15, ty = tid >> 4;
    const int px = tileX*TILE + tx, py = tileY*TILE + ty;

    const float xp = (2.0f*(float)px + 1.0f - 256.0f) * (1.0f/256.0f);
    const float yp = (2.0f*(float)(255 - py) + 1.0f - 256.0f) * (1.0f/256.0f);

    const float tbx0 = (2.0f*(float)(tileX*TILE)          + 1.0f - 256.0f) * (1.0f/256.0f);
    const float tbx1 = (2.0f*(float)(tileX*TILE + TILE-1) + 1.0f - 256.0f) * (1.0f/256.0f);
    const float tby1 = (2.0f*(float)(255 - tileY*TILE)           + 1.0f - 256.0f) * (1.0f/256.0f);
    const float tby0 = (2.0f*(float)(255 - (tileY*TILE+TILE-1))  + 1.0f - 256.0f) * (1.0f/256.0f);

    // scene-bbox skip: reduce the 8 per-setup-block bboxes (uniform loads)
    float gmx = 1e30f, gMx = -1e30f, gmy = 1e30f, gMy = -1e30f;
    #pragma unroll
    for (int b = 0; b < 8; ++b) {
        float4 g = gb[b];
        gmx = fminf(gmx, g.x); gMx = fmaxf(gMx, g.y);
        gmy = fminf(gmy, g.z); gMy = fmaxf(gMy, g.w);
    }
    const bool tile_live = !(tbx0 > gMx || tbx1 < gmx || tby0 > gMy || tby1 < gmy);

    if (tile_live) {
        const int fbase = slice*CHUNK;
        if (tid == 0) s_cnt = 0;
        __syncthreads();

        // phase 1: bbox-only cull + compact
        bool hit = false;
        float4 my_bb;
        if (tid < CHUNK) {
            my_bb = bb[fbase + tid];
            hit = (my_bb.x <= tbx1) && (my_bb.y >= tbx0) &&
                  (my_bb.z <= tby1) && (my_bb.w >= tby0);
        }
        const int lane = tid & 63;
        unsigned long long m = __ballot(hit);
        int wbase = 0;
        if (lane == 0 && m) wbase = atomicAdd(&s_cnt, (int)__popcll(m));
        wbase = __shfl(wbase, 0, 64);
        if (hit) {
            int pos = wbase + (int)__popcll(m & ((1ull << lane) - 1ull));
            s_list[pos] = (unsigned short)tid;
        }
        __syncthreads();

        const int cnt = s_cnt;
        if (cnt > 0) {
            // phase 2: gather-stage survivors (compacted)
            if (tid < cnt) {
                int j = fbase + s_list[tid];
                float4 jb = bb[j];
                s_e0[tid]  = e0[j];
                s_e1[tid]  = e1[j];
                s_rz2[tid] = rz2[j];
                s_bby[tid] = make_float2(jb.z, jb.w);
            }
            __syncthreads();

            // phase 3: eval; wave covers a 16x4 row band -> y-band skip
            const int wv = tid >> 6;
            const int pyTop = tileY*TILE + wv*4;
            const float band_ymax = (2.0f*(float)(255 - pyTop)       + 1.0f - 256.0f) * (1.0f/256.0f);
            const float band_ymin = (2.0f*(float)(255 - (pyTop + 3)) + 1.0f - 256.0f) * (1.0f/256.0f);

            float zmin0 = FAR_P, zmin1 = FAR_P;
            int k = 0;
            for (; k + 2 <= cnt; k += 2) {
                float2 by0 = s_bby[k], by1 = s_bby[k+1];
                if (by0.x <= band_ymax && by0.y >= band_ymin) EVAL(k,   zmin0);
                if (by1.x <= band_ymax && by1.y >= band_ymin) EVAL(k+1, zmin1);
            }
            if (k < cnt) {
                float2 by = s_bby[k];
                if (by.x <= band_ymax && by.y >= band_ymin) EVAL(k, zmin0);
            }
            float zmin = fminf(zmin0, zmin1);
            if (zmin < FAR_P)
                atomicMin(&zbuf[py*ISZ + px], __float_as_int(zmin));
        }
    }

    // ---- tail: tile completion counter + fused 2x2 downsample ----
    __syncthreads();   // drains this block's atomicMins (vmcnt) for all waves
    if (tid == 0) {
        __threadfence();
        s_old = atomicAdd(&tilecnt[tileL], 1);
    }
    __syncthreads();
    if (s_old == SLICES - 1 && tid < 64) {
        int oy = tid >> 3, ox = tid & 7;
        int b00 = (tileY*TILE + 2*oy)*ISZ + (tileX*TILE + 2*ox);
        // device-scope atomic loads: see all blocks' atomicMins at L2
        float z00 = __int_as_float(atomicOr(&zbuf[b00], 0));
        float z01 = __int_as_float(atomicOr(&zbuf[b00 + 1], 0));
        float z10 = __int_as_float(atomicOr(&zbuf[b00 + ISZ], 0));
        float z11 = __int_as_float(atomicOr(&zbuf[b00 + ISZ + 1], 0));
        out[(tileY*8 + oy)*OSZ + (tileX*8 + ox)] = ((z00 + z01) + (z10 + z11)) * 0.25f;
    }
}

extern "C" void kernel_launch(void* const* d_in, const int* in_sizes, int n_in,
                              void* d_out, int out_size, void* d_ws, size_t ws_size,
                              hipStream_t stream)
{
    const float* verts = (const float*)d_in[0];
    const int*   faces = (const int*)  d_in[1];
    const float* Km    = (const float*)d_in[2];
    const float* Rm    = (const float*)d_in[3];
    const float* tv    = (const float*)d_in[4];
    const float* dc    = (const float*)d_in[5];
    float* out = (float*)d_out;

    char* ws = (char*)d_ws;
    float4* e0   = (float4*)ws;     ws += NF*sizeof(float4);
    float4* e1   = (float4*)ws;     ws += NF*sizeof(float4);
    float4* bbx  = (float4*)ws;     ws += NF*sizeof(float4);
    float4* gb   = (float4*)ws;     ws += 8*sizeof(float4);
    float*  rz2  = (float*)ws;      ws += NF*sizeof(float);
    int*    zbuf = (int*)ws;        ws += ISZ*ISZ*sizeof(int);
    int*    tcnt = (int*)ws;        ws += 256*sizeof(int);

    setup_kernel<<<(ISZ*ISZ)/256, 256, 0, stream>>>(faces, verts, Km, Rm, tv, dc,
                                                    e0, e1, rz2, bbx, zbuf, tcnt, gb);
    raster_kernel<<<(ISZ/TILE)*(ISZ/TILE)*SLICES, 256, 0, stream>>>(e0, e1, rz2, bbx, gb,
                                                                    zbuf, tcnt, out);
}

// Round 5
// 29.548 us; speedup vs baseline: 2.7787x; 2.7787x over previous
//
#include <hip/hip_runtime.h>

#define NV 4096
#define NF 2048
#define ISZ 256
#define OSZ 128
#define TILE 16
#define SLICES 32
#define CHUNK 64           // NF / SLICES
#define FAR_P 100.0f
#define NEAR_P 0.1f

// ---------------- projection ----------------
__device__ __forceinline__ float3 project_one(
    const float* __restrict__ verts, int i,
    const float* __restrict__ Km, const float* __restrict__ Rm,
    const float* __restrict__ tv, const float* __restrict__ dc)
{
    float x = verts[3*i+0], y = verts[3*i+1], z = verts[3*i+2];
    float vx = x*Rm[0] + y*Rm[1] + z*Rm[2] + tv[0];
    float vy = x*Rm[3] + y*Rm[4] + z*Rm[5] + tv[1];
    float vz = x*Rm[6] + y*Rm[7] + z*Rm[8] + tv[2];
    float zd = vz + 1e-5f;
    float x_ = vx / zd;
    float y_ = vy / zd;
    float r2 = x_*x_ + y_*y_;
    float k1 = dc[0], k2 = dc[1], p1 = dc[2], p2 = dc[3], k3 = dc[4];
    float radial = 1.0f + k1*r2 + k2*r2*r2 + k3*r2*r2*r2;
    float x__ = x_*radial + 2.0f*p1*x_*y_ + p2*(r2 + 2.0f*x_*x_);
    float y__ = y_*radial + p1*(r2 + 2.0f*y_*y_) + 2.0f*p2*x_*y_;
    float u  = x__*Km[0] + y__*Km[1] + Km[2];
    float vv = x__*Km[3] + y__*Km[4] + Km[5];
    vv = 1024.0f - vv;
    u  = 2.0f*(u  - 512.0f) / 1024.0f;
    vv = 2.0f*(vv - 512.0f) / 1024.0f;
    return make_float3(u, vv, vz);
}

// ---------------- kernel 1: setup + zbuf init (fused) ----------------
__global__ __launch_bounds__(256) void setup_kernel(
    const int* __restrict__ faces, const float* __restrict__ verts,
    const float* __restrict__ Km, const float* __restrict__ Rm,
    const float* __restrict__ tv, const float* __restrict__ dc,
    float4* __restrict__ e0, float4* __restrict__ e1,
    float* __restrict__ rz2, float4* __restrict__ bb,
    int* __restrict__ zbuf, float4* __restrict__ gb)
{
    const int tid = threadIdx.x, bid = blockIdx.x;
    zbuf[bid*256 + tid] = __float_as_int(FAR_P);
    if (bid >= NF/256) return;

    int f = bid*256 + tid;
    float3 p0 = project_one(verts, faces[3*f+0], Km, Rm, tv, dc);
    float3 p1 = project_one(verts, faces[3*f+1], Km, Rm, tv, dc);
    float3 p2 = project_one(verts, faces[3*f+2], Km, Rm, tv, dc);
    float minx = fminf(p0.x, fminf(p1.x, p2.x)) - 1e-4f;
    float maxx = fmaxf(p0.x, fmaxf(p1.x, p2.x)) + 1e-4f;
    float miny = fminf(p0.y, fminf(p1.y, p2.y)) - 1e-4f;
    float maxy = fmaxf(p0.y, fmaxf(p1.y, p2.y)) + 1e-4f;
    e0[f]  = make_float4(p0.x, p0.y, p1.x, p1.y);
    e1[f]  = make_float4(p2.x, p2.y, 1.0f/p0.z, 1.0f/p1.z);
    rz2[f] = 1.0f/p2.z;
    bb[f]  = make_float4(minx, maxx, miny, maxy);

    // block-level scene bbox -> gb[bid] (no atomics)
    float bmx = minx, bMx = maxx, bmy = miny, bMy = maxy;
    #pragma unroll
    for (int off = 32; off; off >>= 1) {
        bmx = fminf(bmx, __shfl_xor(bmx, off));
        bMx = fmaxf(bMx, __shfl_xor(bMx, off));
        bmy = fminf(bmy, __shfl_xor(bmy, off));
        bMy = fmaxf(bMy, __shfl_xor(bMy, off));
    }
    __shared__ float4 s_w[4];
    if ((tid & 63) == 0) s_w[tid >> 6] = make_float4(bmx, bMx, bmy, bMy);
    __syncthreads();
    if (tid == 0) {
        float4 a = s_w[0];
        #pragma unroll
        for (int w = 1; w < 4; ++w) {
            float4 c = s_w[w];
            a.x = fminf(a.x, c.x); a.y = fmaxf(a.y, c.y);
            a.z = fminf(a.z, c.z); a.w = fmaxf(a.w, c.w);
        }
        gb[bid] = a;
    }
}

// ---------------- kernel 2: sliced tiled rasterizer ----------------
// reference-exact edge/area arithmetic — do not reorder
#define EVAL(K, ZM) { \
    float4 q0 = s_e0[K]; float4 q1 = s_e1[K]; float rz = s_rz2[K]; \
    float dx0 = q0.x - xp, dy0 = q0.y - yp; \
    float dx1 = q0.z - xp, dy1 = q0.w - yp; \
    float dx2 = q1.x - xp, dy2 = q1.y - yp; \
    float w0 = dx1*dy2 - dx2*dy1; \
    float w1 = dx2*dy0 - dx0*dy2; \
    float w2 = dx0*dy1 - dx1*dy0; \
    float area = (w0 + w1) + w2; \
    bool ok = fabsf(area) > 1e-10f; \
    float inv = __builtin_amdgcn_rcpf(ok ? area : 1.0f); \
    float b0 = w0*inv, b1 = w1*inv, b2 = w2*inv; \
    bool inside = ok && (b0 >= 0.0f) && (b1 >= 0.0f) && (b2 >= 0.0f); \
    float zinv = b0*q1.z + b1*q1.w + b2*rz; \
    float zz = (fabsf(zinv) > 1e-10f) ? __builtin_amdgcn_rcpf(zinv) : 1.0f; \
    bool valid = inside && (zz > NEAR_P) && (zz < FAR_P); \
    ZM = fminf(ZM, valid ? zz : FAR_P); }

#define BEVAL(K, ZM) { \
    float2 by = s_bby[K]; \
    if (by.x <= band_ymax && by.y >= band_ymin) EVAL(K, ZM); }

__global__ __launch_bounds__(256) void raster_kernel(
    const float4* __restrict__ e0, const float4* __restrict__ e1,
    const float* __restrict__ rz2, const float4* __restrict__ bb,
    const float4* __restrict__ gb, int* __restrict__ zbuf)
{
    __shared__ float4 s_e0[CHUNK];
    __shared__ float4 s_e1[CHUNK];
    __shared__ float  s_rz2[CHUNK];
    __shared__ float2 s_bby[CHUNK];
    __shared__ unsigned short s_list[CHUNK];
    __shared__ int s_cnt;

    const int tid  = threadIdx.x;
    const int bid  = blockIdx.x;
    const int slice = bid & (SLICES - 1);
    const int tileL = bid >> 5;
    const int tileX = tileL & 15, tileY = tileL >> 4;
    const int tx = tid & 15, ty = tid >> 4;
    const int px = tileX*TILE + tx, py = tileY*TILE + ty;

    const float xp = (2.0f*(float)px + 1.0f - 256.0f) * (1.0f/256.0f);
    const float yp = (2.0f*(float)(255 - py) + 1.0f - 256.0f) * (1.0f/256.0f);

    const float tbx0 = (2.0f*(float)(tileX*TILE)          + 1.0f - 256.0f) * (1.0f/256.0f);
    const float tbx1 = (2.0f*(float)(tileX*TILE + TILE-1) + 1.0f - 256.0f) * (1.0f/256.0f);
    const float tby1 = (2.0f*(float)(255 - tileY*TILE)           + 1.0f - 256.0f) * (1.0f/256.0f);
    const float tby0 = (2.0f*(float)(255 - (tileY*TILE+TILE-1))  + 1.0f - 256.0f) * (1.0f/256.0f);

    // scene-bbox skip (uniform loads of the 8 per-setup-block bboxes)
    float gmx = 1e30f, gMx = -1e30f, gmy = 1e30f, gMy = -1e30f;
    #pragma unroll
    for (int b = 0; b < 8; ++b) {
        float4 g = gb[b];
        gmx = fminf(gmx, g.x); gMx = fmaxf(gMx, g.y);
        gmy = fminf(gmy, g.z); gMy = fmaxf(gMy, g.w);
    }
    if (tbx0 > gMx || tbx1 < gmx || tby0 > gMy || tby1 < gmy) return;

    const int fbase = slice*CHUNK;
    if (tid == 0) s_cnt = 0;
    __syncthreads();

    // phase 1: bbox-only cull + compact (CHUNK=64 -> wave 0 only)
    bool hit = false;
    if (tid < CHUNK) {
        float4 my_bb = bb[fbase + tid];
        hit = (my_bb.x <= tbx1) && (my_bb.y >= tbx0) &&
              (my_bb.z <= tby1) && (my_bb.w >= tby0);
    }
    const int lane = tid & 63;
    unsigned long long m = __ballot(hit);
    int wbase = 0;
    if (lane == 0 && m) wbase = atomicAdd(&s_cnt, (int)__popcll(m));
    wbase = __shfl(wbase, 0, 64);
    if (hit) {
        int pos = wbase + (int)__popcll(m & ((1ull << lane) - 1ull));
        s_list[pos] = (unsigned short)tid;
    }
    __syncthreads();

    const int cnt = s_cnt;
    if (cnt == 0) return;

    // phase 2: gather-stage survivors (compacted)
    if (tid < cnt) {
        int j = fbase + s_list[tid];
        float4 jb = bb[j];
        s_e0[tid]  = e0[j];
        s_e1[tid]  = e1[j];
        s_rz2[tid] = rz2[j];
        s_bby[tid] = make_float2(jb.z, jb.w);
    }
    __syncthreads();

    // phase 3: eval, 4x unroll, 4 accumulators; wave covers 16x4 band
    const int wv = tid >> 6;
    const int pyTop = tileY*TILE + wv*4;
    const float band_ymax = (2.0f*(float)(255 - pyTop)       + 1.0f - 256.0f) * (1.0f/256.0f);
    const float band_ymin = (2.0f*(float)(255 - (pyTop + 3)) + 1.0f - 256.0f) * (1.0f/256.0f);

    float zmin0 = FAR_P, zmin1 = FAR_P, zmin2 = FAR_P, zmin3 = FAR_P;
    int k = 0;
    for (; k + 4 <= cnt; k += 4) {
        BEVAL(k,   zmin0);
        BEVAL(k+1, zmin1);
        BEVAL(k+2, zmin2);
        BEVAL(k+3, zmin3);
    }
    for (; k < cnt; ++k) BEVAL(k, zmin0);
    float zmin = fminf(fminf(zmin0, zmin1), fminf(zmin2, zmin3));

    if (zmin < FAR_P)
        atomicMin(&zbuf[py*ISZ + px], __float_as_int(zmin));
}

// ---------------- kernel 3: 2x2 AA downsample ----------------
__global__ __launch_bounds__(256) void down_kernel(
    const int* __restrict__ zbuf, float* __restrict__ out)
{
    int i = blockIdx.x * 256 + threadIdx.x;        // 0 .. 128*128-1
    int ox = i & (OSZ-1), oy = i >> 7;
    int base = (2*oy)*ISZ + 2*ox;
    float z00 = __int_as_float(zbuf[base]);
    float z01 = __int_as_float(zbuf[base + 1]);
    float z10 = __int_as_float(zbuf[base + ISZ]);
    float z11 = __int_as_float(zbuf[base + ISZ + 1]);
    out[i] = ((z00 + z01) + (z10 + z11)) * 0.25f;
}

extern "C" void kernel_launch(void* const* d_in, const int* in_sizes, int n_in,
                              void* d_out, int out_size, void* d_ws, size_t ws_size,
                              hipStream_t stream)
{
    const float* verts = (const float*)d_in[0];
    const int*   faces = (const int*)  d_in[1];
    const float* Km    = (const float*)d_in[2];
    const float* Rm    = (const float*)d_in[3];
    const float* tv    = (const float*)d_in[4];
    const float* dc    = (const float*)d_in[5];
    float* out = (float*)d_out;

    char* ws = (char*)d_ws;
    float4* e0   = (float4*)ws;     ws += NF*sizeof(float4);
    float4* e1   = (float4*)ws;     ws += NF*sizeof(float4);
    float4* bbx  = (float4*)ws;     ws += NF*sizeof(float4);
    float4* gb   = (float4*)ws;     ws += 8*sizeof(float4);
    float*  rz2  = (float*)ws;      ws += NF*sizeof(float);
    int*    zbuf = (int*)ws;        ws += ISZ*ISZ*sizeof(int);

    setup_kernel<<<(ISZ*ISZ)/256, 256, 0, stream>>>(faces, verts, Km, Rm, tv, dc,
                                                    e0, e1, rz2, bbx, zbuf, gb);
    raster_kernel<<<(ISZ/TILE)*(ISZ/TILE)*SLICES, 256, 0, stream>>>(e0, e1, rz2, bbx, gb, zbuf);
    down_kernel <<<(OSZ*OSZ)/256, 256, 0, stream>>>(zbuf, out);
}